// Round 1
// baseline (71.312 us; speedup 1.0000x reference)
//
#include <hip/hip_runtime.h>
#include <math.h>

// Problem constants (from reference)
#define BB 16
#define CC 8
#define TT 512
#define LL 24
#define SSTRIDE 2
#define NN 64
#define MM 245   // (T - L)/STRIDE + 1

// One block per (b, c). 256 threads: n = tid>>2 in [0,64), sub = tid&3.
// Each thread strides m by 4; weights for its n live in 24 registers.
// Reduce min(d)/max(p) across the 4 sub-lanes via shuffle.
__global__ __launch_bounds__(256) void shapelet_kernel(
    const float* __restrict__ x,    // (B, C, T)
    const float* __restrict__ w,    // (N, C, L)
    const float* __restrict__ pcm,  // (C, M)
    float* __restrict__ out)        // [B*N*C] max_p then [B*N*C] d_min
{
    __shared__ float xs[TT];
    __shared__ float pen[MM];

    const int bc  = blockIdx.x;
    const int b   = bc / CC;
    const int c   = bc % CC;
    const int tid = threadIdx.x;

    // Stage x row (512 floats) and penalty row (245 floats) in LDS.
    for (int i = tid; i < TT; i += 256) xs[i]  = x[(b * CC + c) * TT + i];
    for (int i = tid; i < MM; i += 256) pen[i] = pcm[c * MM + i];
    __syncthreads();

    const int n   = tid >> 2;
    const int sub = tid & 3;

    // Weights for this (n, c) into registers (fully unrolled -> no LDS/VMEM in hot loop).
    float wr[LL];
    #pragma unroll
    for (int l = 0; l < LL; ++l) wr[l] = w[(n * CC + c) * LL + l];

    float dmin = INFINITY;
    float pmax = -INFINITY;

    for (int m = sub; m < MM; m += 4) {
        const float* xp = &xs[m * SSTRIDE];
        float s = 0.0f;
        #pragma unroll
        for (int l = 0; l < LL; ++l) s += fabsf(xp[l] - wr[l]);
        const float d = s * (1.0f / LL) * pen[m];
        const float p = __expf(-d * d);
        dmin = fminf(dmin, d);
        pmax = fmaxf(pmax, p);
    }

    // Butterfly reduce over the 4 sub-lanes (adjacent lanes within the wave).
    #pragma unroll
    for (int off = 1; off < 4; off <<= 1) {
        dmin = fminf(dmin, __shfl_xor(dmin, off));
        pmax = fmaxf(pmax, __shfl_xor(pmax, off));
    }

    if (sub == 0) {
        const int oi = (b * NN + n) * CC + c;
        out[oi] = pmax;                  // max_p, laid out (B, N, C) flat
        out[BB * NN * CC + oi] = dmin;   // d_min, same layout, second output
    }
}

extern "C" void kernel_launch(void* const* d_in, const int* in_sizes, int n_in,
                              void* d_out, int out_size, void* d_ws, size_t ws_size,
                              hipStream_t stream) {
    const float* x   = (const float*)d_in[0];
    const float* w   = (const float*)d_in[1];
    const float* pcm = (const float*)d_in[2];
    float* out = (float*)d_out;
    shapelet_kernel<<<BB * CC, 256, 0, stream>>>(x, w, pcm, out);
}

// Round 2
// 63.996 us; speedup vs baseline: 1.1143x; 1.1143x over previous
//
#include <hip/hip_runtime.h>
#include <math.h>

// Problem constants (from reference)
#define BB 16
#define CC 8
#define TT 512
#define LL 24
#define SSTRIDE 2
#define NN 64
#define MM 245          // (T - L)/STRIDE + 1
#define QQ 4            // m-range split into quarters
#define MQ 62           // m's per quarter (last gets 59)
#define OUT1 (BB * NN * CC)   // 8192 elements per output tensor

// Stage 1: one block per (b, c, q). 512 threads: n = tid>>3, sub = tid&7.
// Each thread covers ~8 m's of its quarter; weights in 24 registers; 4
// independent accumulators to break the dependency chain. Per-n min/max
// reduced over the 8 sub-lanes via shuffle, written to ws partials.
__global__ __launch_bounds__(512) void shapelet_partial(
    const float* __restrict__ x,          // (B, C, T)
    const float* __restrict__ w,          // (N, C, L)
    const float* __restrict__ pcm,        // (C, M)
    float* __restrict__ pmax_part,        // [QQ][OUT1]
    float* __restrict__ dmin_part)        // [QQ][OUT1]
{
    __shared__ float xs[2 * (MQ - 1) + LL];   // 146 floats
    __shared__ float pen[MQ];

    const int blk = blockIdx.x;               // (b*CC + c)*QQ + q
    const int q   = blk & (QQ - 1);
    const int bc  = blk >> 2;
    const int b   = bc / CC;
    const int c   = bc % CC;
    const int tid = threadIdx.x;

    const int m0   = q * MQ;
    const int m1   = (m0 + MQ < MM) ? (m0 + MQ) : MM;
    const int nm   = m1 - m0;                 // 62,62,62,59
    const int xlen = 2 * (nm - 1) + LL;       // <=146

    const float* xrow = x + (b * CC + c) * TT + SSTRIDE * m0;
    for (int i = tid; i < xlen; i += 512) xs[i]  = xrow[i];
    for (int i = tid; i < nm;   i += 512) pen[i] = pcm[c * MM + m0 + i];
    __syncthreads();

    const int n   = tid >> 3;
    const int sub = tid & 7;

    float wr[LL];
    #pragma unroll
    for (int l = 0; l < LL; ++l) wr[l] = w[(n * CC + c) * LL + l];

    float dmin = INFINITY;
    float pmax = -INFINITY;

    for (int lm = sub; lm < nm; lm += 8) {
        const float* xp = &xs[SSTRIDE * lm];
        float s0 = 0.0f, s1 = 0.0f, s2 = 0.0f, s3 = 0.0f;
        #pragma unroll
        for (int l = 0; l < LL; l += 4) {
            s0 += fabsf(xp[l + 0] - wr[l + 0]);
            s1 += fabsf(xp[l + 1] - wr[l + 1]);
            s2 += fabsf(xp[l + 2] - wr[l + 2]);
            s3 += fabsf(xp[l + 3] - wr[l + 3]);
        }
        const float d = ((s0 + s1) + (s2 + s3)) * (1.0f / LL) * pen[lm];
        const float p = __expf(-d * d);
        dmin = fminf(dmin, d);
        pmax = fmaxf(pmax, p);
    }

    // Reduce across the 8 sub-lanes (contiguous lanes within the wave).
    #pragma unroll
    for (int off = 1; off < 8; off <<= 1) {
        dmin = fminf(dmin, __shfl_xor(dmin, off));
        pmax = fmaxf(pmax, __shfl_xor(pmax, off));
    }

    if (sub == 0) {
        const int oi = (b * NN + n) * CC + c;
        pmax_part[q * OUT1 + oi] = pmax;
        dmin_part[q * OUT1 + oi] = dmin;
    }
}

// Stage 2: combine the QQ partials per output element.
__global__ __launch_bounds__(256) void shapelet_reduce(
    const float* __restrict__ pmax_part,
    const float* __restrict__ dmin_part,
    float* __restrict__ out)
{
    const int oi = blockIdx.x * 256 + threadIdx.x;
    if (oi >= OUT1) return;
    float pm = -INFINITY, dm = INFINITY;
    #pragma unroll
    for (int q = 0; q < QQ; ++q) {
        pm = fmaxf(pm, pmax_part[q * OUT1 + oi]);
        dm = fminf(dm, dmin_part[q * OUT1 + oi]);
    }
    out[oi] = pm;              // max_p, (B,N,C) flat
    out[OUT1 + oi] = dm;       // d_min
}

extern "C" void kernel_launch(void* const* d_in, const int* in_sizes, int n_in,
                              void* d_out, int out_size, void* d_ws, size_t ws_size,
                              hipStream_t stream) {
    const float* x   = (const float*)d_in[0];
    const float* w   = (const float*)d_in[1];
    const float* pcm = (const float*)d_in[2];
    float* out = (float*)d_out;

    float* pmax_part = (float*)d_ws;                 // QQ*OUT1 floats
    float* dmin_part = pmax_part + QQ * OUT1;        // QQ*OUT1 floats

    shapelet_partial<<<BB * CC * QQ, 512, 0, stream>>>(x, w, pcm, pmax_part, dmin_part);
    shapelet_reduce<<<(OUT1 + 255) / 256, 256, 0, stream>>>(pmax_part, dmin_part, out);
}

// Round 3
// 62.936 us; speedup vs baseline: 1.1331x; 1.0168x over previous
//
#include <hip/hip_runtime.h>
#include <math.h>

// Problem constants (from reference)
#define BB 16
#define CC 8
#define TT 512
#define LL 24
#define SSTRIDE 2
#define NN 64
#define MM 245              // (T - L)/STRIDE + 1
#define OUT1 (BB * NN * CC) // 8192 elements per output tensor

// Single fused kernel. Grid = B*C*8 blocks of 256 threads.
// Block owns (b, c, n0=ns*8 .. n0+7). Thread: n = n0 + tid>>5, sub = tid&31,
// covering m = 8*sub .. 8*sub+7 (consecutive -> x window of 40 floats lives
// in registers; no LDS, no syncthreads, no workspace).
// Key algebra: d >= 0  =>  max_m exp(-d^2) = exp(-(min_m d)^2); exp runs
// ONCE per output after the 32-lane min-reduction.
__global__ __launch_bounds__(256) void shapelet_fused(
    const float* __restrict__ x,    // (B, C, T)
    const float* __restrict__ w,    // (N, C, L)
    const float* __restrict__ pcm,  // (C, M)
    float* __restrict__ out)        // [OUT1] max_p then [OUT1] d_min, (B,N,C)
{
    const int tid = threadIdx.x;
    const int blk = blockIdx.x;          // b*64 + c*8 + ns
    const int ns  = blk & 7;
    const int c   = (blk >> 3) & 7;
    const int b   = blk >> 6;

    const int n   = ns * 8 + (tid >> 5);
    const int sub = tid & 31;

    // Weights for (n, c) -> 24 registers. Base is 96*(n*C+c) bytes: 16B aligned.
    float wr[LL];
    {
        const float4* wp = (const float4*)(w + (n * CC + c) * LL);
        #pragma unroll
        for (int i = 0; i < 6; ++i) {
            const float4 v = wp[i];
            wr[4*i+0] = v.x; wr[4*i+1] = v.y; wr[4*i+2] = v.z; wr[4*i+3] = v.w;
        }
    }

    // x window: 40 floats starting at 16*sub (covers m = 8*sub .. 8*sub+7).
    // Clamp each float4 to the row end; clamped values are only consumed by
    // masked-out (m >= M) iterations. Indexing into xw is fully static.
    const float* row = x + (b * CC + c) * TT;
    float xw[40];
    #pragma unroll
    for (int i = 0; i < 10; ++i) {
        int xo = 16 * sub + 4 * i;
        if (xo > TT - 4) xo = TT - 4;
        const float4 v = *(const float4*)(row + xo);
        xw[4*i+0] = v.x; xw[4*i+1] = v.y; xw[4*i+2] = v.z; xw[4*i+3] = v.w;
    }

    const float* prow = pcm + c * MM;
    float dmin = INFINITY;

    #pragma unroll
    for (int k = 0; k < 8; ++k) {
        const int m = 8 * sub + k;
        const float pv = prow[m < MM ? m : MM - 1];
        float s0 = 0.0f, s1 = 0.0f, s2 = 0.0f, s3 = 0.0f;
        #pragma unroll
        for (int l = 0; l < LL; l += 4) {
            s0 += fabsf(xw[2*k + l + 0] - wr[l + 0]);
            s1 += fabsf(xw[2*k + l + 1] - wr[l + 1]);
            s2 += fabsf(xw[2*k + l + 2] - wr[l + 2]);
            s3 += fabsf(xw[2*k + l + 3] - wr[l + 3]);
        }
        float d = ((s0 + s1) + (s2 + s3)) * (1.0f / LL) * pv;
        d = (m < MM) ? d : INFINITY;     // mask tail (sub>=30 partial/empty)
        dmin = fminf(dmin, d);
    }

    // Min over the 32 sub-lanes (aligned 32-group stays inside the wave).
    #pragma unroll
    for (int off = 1; off < 32; off <<= 1)
        dmin = fminf(dmin, __shfl_xor(dmin, off));

    if (sub == 0) {
        const int oi = (b * NN + n) * CC + c;
        out[oi]        = __expf(-dmin * dmin);  // max_p = exp(-(min d)^2)
        out[OUT1 + oi] = dmin;                  // d_min
    }
}

extern "C" void kernel_launch(void* const* d_in, const int* in_sizes, int n_in,
                              void* d_out, int out_size, void* d_ws, size_t ws_size,
                              hipStream_t stream) {
    const float* x   = (const float*)d_in[0];
    const float* w   = (const float*)d_in[1];
    const float* pcm = (const float*)d_in[2];
    float* out = (float*)d_out;
    shapelet_fused<<<BB * CC * 8, 256, 0, stream>>>(x, w, pcm, out);
}